// Round 5
// baseline (3573.639 us; speedup 1.0000x reference)
//
#include <hip/hip_runtime.h>

// APPNP propagation: h <- (1-alpha) * A @ h + alpha * x, K=10 steps.
// R4: feature-sliced SpMM. R3 post-mortem: FETCH = 256 B/edge (~0% L2 hit on
// the random gather; 25.6 MB h footprint >> 4 MB/XCD L2), bound at ~3.5 TB/s
// of L2-miss traffic. Fix: store h slice-major in 8 slices of 16 features
// (3.2 MB/slice, fits one XCD L2); slice = blockIdx.x & 7 pins each slice to
// one XCD (round-robin dispatch heuristic). Edge list re-streamed per slice
// (8x12.8 MB, nontemporal), xs/dst nontemporal so L2 holds only the slice.
// Wave = 1 row: 8 edges x 8 lanes (2 feats/lane), shfl_xor reduce over edges.
// Ping-pong A/B slice-major bf16; k=9 writes fp32 node-major to d_out.

#define N_NODES 100000
#define N_EDGES 1600000
#define D_FEAT  128
#define ALPHA   0.1f
#define K_STEPS 10

#define SCAN_ELEMS 512
#define SCAN_NBLK  ((N_NODES + SCAN_ELEMS - 1) / SCAN_ELEMS)  // 196

#define NSLICE 8
#define WAVES_PER_SLICE 1024
#define SLICE_BLOCKS (NSLICE * WAVES_PER_SLICE / 4)  // 2048 blocks of 4 waves

typedef __attribute__((ext_vector_type(2))) float f32x2;

static __device__ __forceinline__ float bf2f(unsigned u16) {
    return __uint_as_float(u16 << 16);
}
static __device__ __forceinline__ unsigned f2bf(float f) {
    unsigned u = __float_as_uint(f);
    return (u + 0x7fffu + ((u >> 16) & 1u)) >> 16;  // round-to-nearest-even
}

// ---------- CSR build ----------

__global__ __launch_bounds__(256) void hist_kernel(const int* __restrict__ rows,
                                                   int* __restrict__ deg) {
    int e = blockIdx.x * 256 + threadIdx.x;
    if (e < N_EDGES) atomicAdd(&deg[rows[e]], 1);
}

__global__ __launch_bounds__(256) void scan_partial(const int* __restrict__ deg,
                                                    int* __restrict__ partial) {
    __shared__ int s[256];
    int b = blockIdx.x, t = threadIdx.x;
    int i0 = b * SCAN_ELEMS + t * 2;
    int v0 = (i0 < N_NODES) ? deg[i0] : 0;
    int v1 = (i0 + 1 < N_NODES) ? deg[i0 + 1] : 0;
    s[t] = v0 + v1;
    __syncthreads();
    for (int off = 128; off > 0; off >>= 1) {
        if (t < off) s[t] += s[t + off];
        __syncthreads();
    }
    if (t == 0) partial[b] = s[0];
}

__global__ __launch_bounds__(256) void scan_top(int* __restrict__ partial) {
    __shared__ int s[256];
    int t = threadIdx.x;
    s[t] = (t < SCAN_NBLK) ? partial[t] : 0;
    __syncthreads();
    for (int off = 1; off < 256; off <<= 1) {
        int v = (t >= off) ? s[t - off] : 0;
        __syncthreads();
        s[t] += v;
        __syncthreads();
    }
    if (t < SCAN_NBLK) partial[t] = (t == 0) ? 0 : s[t - 1];
}

__global__ __launch_bounds__(256) void scan_final(int* __restrict__ deg_cursor,
                                                  const int* __restrict__ partial,
                                                  int* __restrict__ row_ptr) {
    __shared__ int s[256];
    int b = blockIdx.x, t = threadIdx.x;
    int i0 = b * SCAN_ELEMS + t * 2;
    int v0 = (i0 < N_NODES) ? deg_cursor[i0] : 0;
    int v1 = (i0 + 1 < N_NODES) ? deg_cursor[i0 + 1] : 0;
    int pair = v0 + v1;
    s[t] = pair;
    __syncthreads();
    for (int off = 1; off < 256; off <<= 1) {
        int v = (t >= off) ? s[t - off] : 0;
        __syncthreads();
        s[t] += v;
        __syncthreads();
    }
    int ex = partial[b] + s[t] - pair;  // exclusive prefix of element 2t
    if (i0 < N_NODES)     { row_ptr[i0] = ex;          deg_cursor[i0] = ex; }
    if (i0 + 1 < N_NODES) { row_ptr[i0 + 1] = ex + v0; deg_cursor[i0 + 1] = ex + v0; }
    if (b == 0 && t == 0) row_ptr[N_NODES] = N_EDGES;
}

__global__ __launch_bounds__(256) void scatter_kernel(const int* __restrict__ rows,
                                                      const int* __restrict__ cols,
                                                      const float* __restrict__ w,
                                                      int* __restrict__ cursor,
                                                      int2* __restrict__ csr) {
    int e = blockIdx.x * 256 + threadIdx.x;
    if (e < N_EDGES) {
        int pos = atomicAdd(&cursor[rows[e]], 1);
        int2 cw;
        cw.x = cols[e];
        cw.y = __float_as_int((1.0f - ALPHA) * w[e]);  // fold 0.9 into the weight
        csr[pos] = cw;
    }
}

// ---------- prep: x (node-major fp32) -> h0, xs (slice-major bf16x2) ----------

__global__ __launch_bounds__(256) void prep_x(const float2* __restrict__ x2,
                                              unsigned* __restrict__ h0,
                                              unsigned* __restrict__ xs) {
    int t = blockIdx.x * 256 + threadIdx.x;  // over N*64 feature pairs
    if (t >= N_NODES * 64) return;
    int n = t >> 6;
    int p = t & 63;   // pair index within node
    int s = p >> 3;
    int j = p & 7;
    float2 v = x2[t];  // coalesced: node-major
    size_t o = ((size_t)s * N_NODES + n) * 8 + j;
    h0[o] = f2bf(v.x) | (f2bf(v.y) << 16);
    xs[o] = f2bf(ALPHA * v.x) | (f2bf(ALPHA * v.y) << 16);
}

// ---------- propagation step: feature-sliced, one wave per row ----------
// lane = g*8 + j: g = edge group (8 edges in parallel), j = feature pair.

template <bool FINAL>
__global__ __launch_bounds__(256) void slice_spmm(const int* __restrict__ row_ptr,
                                                  const long long* __restrict__ csr,
                                                  const unsigned* __restrict__ xs,
                                                  const unsigned* __restrict__ hsrc,
                                                  unsigned* __restrict__ hdst,
                                                  float* __restrict__ fout) {
    int s = blockIdx.x & 7;  // slice -> XCD via round-robin dispatch
    int wid = (blockIdx.x >> 3) * 4 + (threadIdx.x >> 6);  // 0..1023 within slice
    int lane = threadIdx.x & 63;
    int g = lane >> 3;
    int j = lane & 7;
    const unsigned* hs  = hsrc + (size_t)s * N_NODES * 8;  // this slice, 3.2 MB
    const unsigned* xss = xs   + (size_t)s * N_NODES * 8;
    unsigned*       hd  = hdst + (size_t)s * N_NODES * 8;

    for (int r = wid; r < N_NODES; r += WAVES_PER_SLICE) {
        int beg = row_ptr[r];
        int end = row_ptr[r + 1];
        float ax = 0.0f, ay = 0.0f;
        for (int e0 = beg; e0 < end; e0 += 8) {
            int e = e0 + g;
            if (e < end) {
                long long cw = __builtin_nontemporal_load(csr + e);  // stream, don't cache
                int col = (int)(unsigned)cw;
                float w = __int_as_float((int)(cw >> 32));
                unsigned hv = hs[(size_t)col * 8 + j];  // temporal: the L2-resident slice
                ax += w * bf2f(hv & 0xffffu);
                ay += w * bf2f(hv >> 16);
            }
        }
        // reduce over edge groups g (bits 3..5 of lane)
        ax += __shfl_xor(ax, 8);  ay += __shfl_xor(ay, 8);
        ax += __shfl_xor(ax, 16); ay += __shfl_xor(ay, 16);
        ax += __shfl_xor(ax, 32); ay += __shfl_xor(ay, 32);
        if (g == 0) {
            unsigned xv = __builtin_nontemporal_load(xss + (size_t)r * 8 + j);
            float ox = ax + bf2f(xv & 0xffffu);
            float oy = ay + bf2f(xv >> 16);
            if (FINAL) {
                f32x2 o; o.x = ox; o.y = oy;
                __builtin_nontemporal_store(o, (f32x2*)fout + (size_t)r * 64 + s * 8 + j);
            } else {
                __builtin_nontemporal_store(f2bf(ox) | (f2bf(oy) << 16),
                                            hd + (size_t)r * 8 + j);
            }
        }
    }
}

// ---------- R3 fallback: node-major bf16 gather (if ws too small) ----------

template <bool SRC_BF, bool DST_BF>
__global__ __launch_bounds__(256) void row_spmm_t(const int* __restrict__ row_ptr,
                                                  const int2* __restrict__ csr,
                                                  const float2* __restrict__ x2,
                                                  const void* __restrict__ src,
                                                  void* __restrict__ dst) {
    int row = (blockIdx.x * 256 + threadIdx.x) >> 6;
    int lane = threadIdx.x & 63;
    if (row >= N_NODES) return;
    int beg = row_ptr[row];
    int end = row_ptr[row + 1];
    float2 xv = x2[(size_t)row * 64 + lane];

    const float2*   sf = (const float2*)src;
    const unsigned* sb = (const unsigned*)src;
    float ax0 = 0, ay0 = 0, ax1 = 0, ay1 = 0, ax2 = 0, ay2 = 0, ax3 = 0, ay3 = 0;

    auto gather = [&](int col) -> float2 {
        if (SRC_BF) {
            unsigned u = sb[(size_t)col * 64 + lane];
            float2 v; v.x = bf2f(u & 0xffffu); v.y = bf2f(u >> 16);
            return v;
        } else {
            return sf[(size_t)col * 64 + lane];
        }
    };

    int j = beg;
    for (; j + 3 < end; j += 4) {
        int2 cw0 = csr[j], cw1 = csr[j + 1], cw2 = csr[j + 2], cw3 = csr[j + 3];
        float2 v0 = gather(cw0.x), v1 = gather(cw1.x), v2 = gather(cw2.x), v3 = gather(cw3.x);
        float w0 = __int_as_float(cw0.y), w1 = __int_as_float(cw1.y);
        float w2 = __int_as_float(cw2.y), w3 = __int_as_float(cw3.y);
        ax0 += w0 * v0.x; ay0 += w0 * v0.y;
        ax1 += w1 * v1.x; ay1 += w1 * v1.y;
        ax2 += w2 * v2.x; ay2 += w2 * v2.y;
        ax3 += w3 * v3.x; ay3 += w3 * v3.y;
    }
    for (; j < end; ++j) {
        int2 cw = csr[j];
        float2 v = gather(cw.x);
        float wv = __int_as_float(cw.y);
        ax0 += wv * v.x; ay0 += wv * v.y;
    }
    float ox = ALPHA * xv.x + (ax0 + ax1) + (ax2 + ax3);
    float oy = ALPHA * xv.y + (ay0 + ay1) + (ay2 + ay3);
    if (DST_BF) {
        ((unsigned*)dst)[(size_t)row * 64 + lane] = f2bf(ox) | (f2bf(oy) << 16);
    } else {
        float2 o; o.x = ox; o.y = oy;
        ((float2*)dst)[(size_t)row * 64 + lane] = o;
    }
}

// ---------- R0 fallback (atomic path) ----------

__global__ __launch_bounds__(256) void init_step(const float4* __restrict__ x,
                                                 float4* __restrict__ dst, int n4) {
    int i = blockIdx.x * 256 + threadIdx.x;
    if (i < n4) {
        float4 v = x[i];
        dst[i] = make_float4(ALPHA * v.x, ALPHA * v.y, ALPHA * v.z, ALPHA * v.w);
    }
}

__global__ __launch_bounds__(256) void edge_scatter(const int* __restrict__ rows,
                                                    const int* __restrict__ cols,
                                                    const float* __restrict__ w,
                                                    const float* __restrict__ h,
                                                    float* __restrict__ dst) {
    unsigned t = blockIdx.x * 256u + threadIdx.x;
    unsigned e = t >> 5;
    unsigned l = t & 31u;
    if (e >= N_EDGES) return;
    int r = rows[e];
    int c = cols[e];
    float we = (1.0f - ALPHA) * w[e];
    const float4* hc = (const float4*)(h + (size_t)c * D_FEAT);
    float4 v = hc[l];
    float* dr = dst + (size_t)r * D_FEAT + (size_t)l * 4;
    unsafeAtomicAdd(dr + 0, we * v.x);
    unsafeAtomicAdd(dr + 1, we * v.y);
    unsafeAtomicAdd(dr + 2, we * v.z);
    unsafeAtomicAdd(dr + 3, we * v.w);
}

extern "C" void kernel_launch(void* const* d_in, const int* in_sizes, int n_in,
                              void* d_out, int out_size, void* d_ws, size_t ws_size,
                              hipStream_t stream) {
    const float* x  = (const float*)d_in[0];
    const int*   ei = (const int*)d_in[1];  // [2, E] flat: rows then cols
    const float* ev = (const float*)d_in[2];
    const int* rows = ei;
    const int* cols = ei + N_EDGES;
    float* out = (float*)d_out;

    size_t off = 0;
    auto take = [&](size_t bytes) {
        size_t o = off;
        off = (off + bytes + 15) & ~(size_t)15;
        return o;
    };
    size_t o_ha      = take((size_t)N_NODES * D_FEAT * 2);  // 25.6 MB slice-major A
    size_t o_hb      = take((size_t)N_NODES * D_FEAT * 2);  // 25.6 MB slice-major B
    size_t o_xs      = take((size_t)N_NODES * D_FEAT * 2);  // 25.6 MB xs = 0.1x
    size_t o_rowptr  = take((size_t)(N_NODES + 1) * 4);
    size_t o_cursor  = take((size_t)N_NODES * 4);
    size_t o_partial = take((size_t)SCAN_NBLK * 4);
    size_t o_csr     = take((size_t)N_EDGES * 8);
    size_t need_slice = off;
    size_t need_r3 = need_slice - (size_t)N_NODES * D_FEAT * 2;  // ~ A+B+meta (reuse layout loosely)

    const int edge_blocks_1t = (N_EDGES + 255) / 256;  // 6250

    char* wsb = (char*)d_ws;
    if (ws_size >= need_slice) {
        unsigned* hA      = (unsigned*)(wsb + o_ha);
        unsigned* hB      = (unsigned*)(wsb + o_hb);
        unsigned* xs      = (unsigned*)(wsb + o_xs);
        int*      row_ptr = (int*)(wsb + o_rowptr);
        int*      cursor  = (int*)(wsb + o_cursor);
        int*      partial = (int*)(wsb + o_partial);
        int2*     csr     = (int2*)(wsb + o_csr);

        hipMemsetAsync(cursor, 0, (size_t)N_NODES * 4, stream);
        hist_kernel<<<edge_blocks_1t, 256, 0, stream>>>(rows, cursor);
        scan_partial<<<SCAN_NBLK, 256, 0, stream>>>(cursor, partial);
        scan_top<<<1, 256, 0, stream>>>(partial);
        scan_final<<<SCAN_NBLK, 256, 0, stream>>>(cursor, partial, row_ptr);
        scatter_kernel<<<edge_blocks_1t, 256, 0, stream>>>(rows, cols, ev, cursor, csr);
        prep_x<<<(N_NODES * 64 + 255) / 256, 256, 0, stream>>>((const float2*)x, hA, xs);

        const long long* csr8 = (const long long*)csr;
        for (int k = 0; k < K_STEPS - 1; ++k) {
            const unsigned* src = (k & 1) ? hB : hA;
            unsigned* dst = (k & 1) ? hA : hB;
            slice_spmm<false><<<SLICE_BLOCKS, 256, 0, stream>>>(row_ptr, csr8, xs,
                                                                src, dst, out);
        }
        // k=9: src = hB (k odd), write fp32 node-major to d_out
        slice_spmm<true><<<SLICE_BLOCKS, 256, 0, stream>>>(row_ptr, csr8, xs,
                                                           hB, hA, out);
    } else if (ws_size >= need_r3) {
        // R3 path: node-major bf16 ping-pong (A,B) + CSR
        unsigned* hA      = (unsigned*)(wsb + o_ha);
        unsigned* hB      = (unsigned*)(wsb + o_hb);
        int*      row_ptr = (int*)(wsb + o_rowptr - (size_t)N_NODES * D_FEAT * 2);
        int*      cursor  = (int*)(wsb + o_cursor - (size_t)N_NODES * D_FEAT * 2);
        int*      partial = (int*)(wsb + o_partial - (size_t)N_NODES * D_FEAT * 2);
        int2*     csr     = (int2*)(wsb + o_csr - (size_t)N_NODES * D_FEAT * 2);

        hipMemsetAsync(cursor, 0, (size_t)N_NODES * 4, stream);
        hist_kernel<<<edge_blocks_1t, 256, 0, stream>>>(rows, cursor);
        scan_partial<<<SCAN_NBLK, 256, 0, stream>>>(cursor, partial);
        scan_top<<<1, 256, 0, stream>>>(partial);
        scan_final<<<SCAN_NBLK, 256, 0, stream>>>(cursor, partial, row_ptr);
        scatter_kernel<<<edge_blocks_1t, 256, 0, stream>>>(rows, cols, ev, cursor, csr);

        const int row_blocks = (N_NODES * 64 + 255) / 256;
        const float2* x2 = (const float2*)x;
        row_spmm_t<false, true><<<row_blocks, 256, 0, stream>>>(row_ptr, csr, x2,
                                                                (const void*)x, hA);
        for (int k = 1; k <= 8; ++k) {
            const void* src = (k & 1) ? (void*)hA : (void*)hB;
            void* dst = (k & 1) ? (void*)hB : (void*)hA;
            row_spmm_t<true, true><<<row_blocks, 256, 0, stream>>>(row_ptr, csr, x2, src, dst);
        }
        row_spmm_t<true, false><<<row_blocks, 256, 0, stream>>>(row_ptr, csr, x2,
                                                                (const void*)hA, (void*)out);
    } else {
        float* wsf = (float*)d_ws;
        const int n4 = N_NODES * D_FEAT / 4;
        const int init_blocks = (n4 + 255) / 256;
        const int edge_blocks = (N_EDGES * 32 + 255) / 256;
        for (int k = 0; k < K_STEPS; ++k) {
            const float* src = (k == 0) ? x : ((k & 1) ? wsf : out);
            float* dst = (k & 1) ? out : wsf;
            init_step<<<init_blocks, 256, 0, stream>>>((const float4*)x, (float4*)dst, n4);
            edge_scatter<<<edge_blocks, 256, 0, stream>>>(rows, cols, ev, src, dst);
        }
    }
}

// Round 6
// 2597.023 us; speedup vs baseline: 1.3761x; 1.3761x over previous
//
#include <hip/hip_runtime.h>

// APPNP propagation: h <- (1-alpha) * A @ h + alpha * x, K=10 steps.
// R5: feature-sliced SpMM (8 slices x 16 feats, 3.2 MB/slice pinned in per-XCD
// L2 via blockIdx&7), restructured for memory-level parallelism.
// R4 post-mortem: slicing cut FETCH 440->123 MB/step (L2 hit confirmed) but
// became per-wave serial-latency bound (1 outstanding gather/lane, nt csr at
// HBM latency, shfl reduce per row) -> 334 us/step.
// R5 kernel: wave = 8 rows x 8 feature-pairs (no reduce), edge loop unrolled
// x8 -> 8 independent csr loads + 8 independent gathers in flight per lane.
// Predication by clamped index + zero weight (no branches).
// Ping-pong A/B slice-major bf16; k=9 writes fp32 node-major to d_out.

#define N_NODES 100000
#define N_EDGES 1600000
#define D_FEAT  128
#define ALPHA   0.1f
#define K_STEPS 10

#define SCAN_ELEMS 512
#define SCAN_NBLK  ((N_NODES + SCAN_ELEMS - 1) / SCAN_ELEMS)  // 196

#define NSLICE 8
#define WAVES_PER_SLICE 1024
#define SLICE_BLOCKS (NSLICE * WAVES_PER_SLICE / 4)  // 2048 blocks of 4 waves
#define N_OCT ((N_NODES + 7) / 8)                    // 12500 row-octets

typedef __attribute__((ext_vector_type(2))) float f32x2;

static __device__ __forceinline__ float bf2f(unsigned u16) {
    return __uint_as_float(u16 << 16);
}
static __device__ __forceinline__ unsigned f2bf(float f) {
    unsigned u = __float_as_uint(f);
    return (u + 0x7fffu + ((u >> 16) & 1u)) >> 16;  // round-to-nearest-even
}

// ---------- CSR build ----------

__global__ __launch_bounds__(256) void hist_kernel(const int* __restrict__ rows,
                                                   int* __restrict__ deg) {
    int e = blockIdx.x * 256 + threadIdx.x;
    if (e < N_EDGES) atomicAdd(&deg[rows[e]], 1);
}

__global__ __launch_bounds__(256) void scan_partial(const int* __restrict__ deg,
                                                    int* __restrict__ partial) {
    __shared__ int s[256];
    int b = blockIdx.x, t = threadIdx.x;
    int i0 = b * SCAN_ELEMS + t * 2;
    int v0 = (i0 < N_NODES) ? deg[i0] : 0;
    int v1 = (i0 + 1 < N_NODES) ? deg[i0 + 1] : 0;
    s[t] = v0 + v1;
    __syncthreads();
    for (int off = 128; off > 0; off >>= 1) {
        if (t < off) s[t] += s[t + off];
        __syncthreads();
    }
    if (t == 0) partial[b] = s[0];
}

__global__ __launch_bounds__(256) void scan_top(int* __restrict__ partial) {
    __shared__ int s[256];
    int t = threadIdx.x;
    s[t] = (t < SCAN_NBLK) ? partial[t] : 0;
    __syncthreads();
    for (int off = 1; off < 256; off <<= 1) {
        int v = (t >= off) ? s[t - off] : 0;
        __syncthreads();
        s[t] += v;
        __syncthreads();
    }
    if (t < SCAN_NBLK) partial[t] = (t == 0) ? 0 : s[t - 1];
}

__global__ __launch_bounds__(256) void scan_final(int* __restrict__ deg_cursor,
                                                  const int* __restrict__ partial,
                                                  int* __restrict__ row_ptr) {
    __shared__ int s[256];
    int b = blockIdx.x, t = threadIdx.x;
    int i0 = b * SCAN_ELEMS + t * 2;
    int v0 = (i0 < N_NODES) ? deg_cursor[i0] : 0;
    int v1 = (i0 + 1 < N_NODES) ? deg_cursor[i0 + 1] : 0;
    int pair = v0 + v1;
    s[t] = pair;
    __syncthreads();
    for (int off = 1; off < 256; off <<= 1) {
        int v = (t >= off) ? s[t - off] : 0;
        __syncthreads();
        s[t] += v;
        __syncthreads();
    }
    int ex = partial[b] + s[t] - pair;  // exclusive prefix of element 2t
    if (i0 < N_NODES)     { row_ptr[i0] = ex;          deg_cursor[i0] = ex; }
    if (i0 + 1 < N_NODES) { row_ptr[i0 + 1] = ex + v0; deg_cursor[i0 + 1] = ex + v0; }
    if (b == 0 && t == 0) row_ptr[N_NODES] = N_EDGES;
}

__global__ __launch_bounds__(256) void scatter_kernel(const int* __restrict__ rows,
                                                      const int* __restrict__ cols,
                                                      const float* __restrict__ w,
                                                      int* __restrict__ cursor,
                                                      int2* __restrict__ csr) {
    int e = blockIdx.x * 256 + threadIdx.x;
    if (e < N_EDGES) {
        int pos = atomicAdd(&cursor[rows[e]], 1);
        int2 cw;
        cw.x = cols[e];
        cw.y = __float_as_int((1.0f - ALPHA) * w[e]);  // fold 0.9 into the weight
        csr[pos] = cw;
    }
}

// ---------- prep: x (node-major fp32) -> h0, xs (slice-major bf16x2) ----------

__global__ __launch_bounds__(256) void prep_x(const float2* __restrict__ x2,
                                              unsigned* __restrict__ h0,
                                              unsigned* __restrict__ xs) {
    int t = blockIdx.x * 256 + threadIdx.x;  // over N*64 feature pairs
    if (t >= N_NODES * 64) return;
    int n = t >> 6;
    int p = t & 63;   // pair index within node
    int s = p >> 3;
    int j = p & 7;
    float2 v = x2[t];  // coalesced: node-major
    size_t o = ((size_t)s * N_NODES + n) * 8 + j;
    h0[o] = f2bf(v.x) | (f2bf(v.y) << 16);
    xs[o] = f2bf(ALPHA * v.x) | (f2bf(ALPHA * v.y) << 16);
}

// ---------- propagation step: feature-sliced, wave = 8 rows x 8 pairs ----------
// lane = g*8 + j: group g owns row oct*8+g; lane j owns feature pair j.
// No cross-lane reduce; unroll x8 over edges for 8 outstanding gathers/lane.

template <bool FINAL>
__global__ __launch_bounds__(256) void slice_spmm(const int* __restrict__ row_ptr,
                                                  const long long* __restrict__ csr,
                                                  const unsigned* __restrict__ xs,
                                                  const unsigned* __restrict__ hsrc,
                                                  unsigned* __restrict__ hdst,
                                                  float* __restrict__ fout) {
    int s = blockIdx.x & 7;  // slice -> XCD via round-robin dispatch
    int wid = (blockIdx.x >> 3) * 4 + (threadIdx.x >> 6);  // 0..1023 within slice
    int lane = threadIdx.x & 63;
    int g = lane >> 3;
    int j = lane & 7;
    const unsigned* hs  = hsrc + (size_t)s * N_NODES * 8;  // this slice, 3.2 MB
    const unsigned* xss = xs   + (size_t)s * N_NODES * 8;
    unsigned*       hd  = hdst + (size_t)s * N_NODES * 8;

    for (int oct = wid; oct < N_OCT; oct += WAVES_PER_SLICE) {
        int r = oct * 8 + g;
        bool vr = (r < N_NODES);
        int beg = 0, end = 0;
        if (vr) {
            beg = row_ptr[r];
            end = row_ptr[r + 1];
        }
        float ax = 0.0f, ay = 0.0f;
        int elast = end - 1;  // valid whenever the loop below runs (beg < end)
        for (int e0 = beg; e0 < end; e0 += 8) {
            long long cw[8];
#pragma unroll
            for (int u = 0; u < 8; ++u)
                cw[u] = __builtin_nontemporal_load(csr + min(e0 + u, elast));
            unsigned hv[8];
#pragma unroll
            for (int u = 0; u < 8; ++u)
                hv[u] = hs[(size_t)(unsigned)cw[u] * 8 + j];  // temporal: L2 slice
#pragma unroll
            for (int u = 0; u < 8; ++u) {
                float w = (e0 + u < end) ? __int_as_float((int)(cw[u] >> 32)) : 0.0f;
                ax += w * bf2f(hv[u] & 0xffffu);
                ay += w * bf2f(hv[u] >> 16);
            }
        }
        if (vr) {
            unsigned xv = __builtin_nontemporal_load(xss + (size_t)r * 8 + j);
            float ox = ax + bf2f(xv & 0xffffu);
            float oy = ay + bf2f(xv >> 16);
            if (FINAL) {
                f32x2 o; o.x = ox; o.y = oy;
                __builtin_nontemporal_store(o, (f32x2*)fout + (size_t)r * 64 + s * 8 + j);
            } else {
                __builtin_nontemporal_store(f2bf(ox) | (f2bf(oy) << 16),
                                            hd + (size_t)r * 8 + j);
            }
        }
    }
}

// ---------- R3 fallback: node-major bf16 gather (if ws too small) ----------

template <bool SRC_BF, bool DST_BF>
__global__ __launch_bounds__(256) void row_spmm_t(const int* __restrict__ row_ptr,
                                                  const int2* __restrict__ csr,
                                                  const float2* __restrict__ x2,
                                                  const void* __restrict__ src,
                                                  void* __restrict__ dst) {
    int row = (blockIdx.x * 256 + threadIdx.x) >> 6;
    int lane = threadIdx.x & 63;
    if (row >= N_NODES) return;
    int beg = row_ptr[row];
    int end = row_ptr[row + 1];
    float2 xv = x2[(size_t)row * 64 + lane];

    const float2*   sf = (const float2*)src;
    const unsigned* sb = (const unsigned*)src;
    float ax0 = 0, ay0 = 0, ax1 = 0, ay1 = 0, ax2 = 0, ay2 = 0, ax3 = 0, ay3 = 0;

    auto gather = [&](int col) -> float2 {
        if (SRC_BF) {
            unsigned u = sb[(size_t)col * 64 + lane];
            float2 v; v.x = bf2f(u & 0xffffu); v.y = bf2f(u >> 16);
            return v;
        } else {
            return sf[(size_t)col * 64 + lane];
        }
    };

    int j = beg;
    for (; j + 3 < end; j += 4) {
        int2 cw0 = csr[j], cw1 = csr[j + 1], cw2 = csr[j + 2], cw3 = csr[j + 3];
        float2 v0 = gather(cw0.x), v1 = gather(cw1.x), v2 = gather(cw2.x), v3 = gather(cw3.x);
        float w0 = __int_as_float(cw0.y), w1 = __int_as_float(cw1.y);
        float w2 = __int_as_float(cw2.y), w3 = __int_as_float(cw3.y);
        ax0 += w0 * v0.x; ay0 += w0 * v0.y;
        ax1 += w1 * v1.x; ay1 += w1 * v1.y;
        ax2 += w2 * v2.x; ay2 += w2 * v2.y;
        ax3 += w3 * v3.x; ay3 += w3 * v3.y;
    }
    for (; j < end; ++j) {
        int2 cw = csr[j];
        float2 v = gather(cw.x);
        float wv = __int_as_float(cw.y);
        ax0 += wv * v.x; ay0 += wv * v.y;
    }
    float ox = ALPHA * xv.x + (ax0 + ax1) + (ax2 + ax3);
    float oy = ALPHA * xv.y + (ay0 + ay1) + (ay2 + ay3);
    if (DST_BF) {
        ((unsigned*)dst)[(size_t)row * 64 + lane] = f2bf(ox) | (f2bf(oy) << 16);
    } else {
        float2 o; o.x = ox; o.y = oy;
        ((float2*)dst)[(size_t)row * 64 + lane] = o;
    }
}

// ---------- R0 fallback (atomic path) ----------

__global__ __launch_bounds__(256) void init_step(const float4* __restrict__ x,
                                                 float4* __restrict__ dst, int n4) {
    int i = blockIdx.x * 256 + threadIdx.x;
    if (i < n4) {
        float4 v = x[i];
        dst[i] = make_float4(ALPHA * v.x, ALPHA * v.y, ALPHA * v.z, ALPHA * v.w);
    }
}

__global__ __launch_bounds__(256) void edge_scatter(const int* __restrict__ rows,
                                                    const int* __restrict__ cols,
                                                    const float* __restrict__ w,
                                                    const float* __restrict__ h,
                                                    float* __restrict__ dst) {
    unsigned t = blockIdx.x * 256u + threadIdx.x;
    unsigned e = t >> 5;
    unsigned l = t & 31u;
    if (e >= N_EDGES) return;
    int r = rows[e];
    int c = cols[e];
    float we = (1.0f - ALPHA) * w[e];
    const float4* hc = (const float4*)(h + (size_t)c * D_FEAT);
    float4 v = hc[l];
    float* dr = dst + (size_t)r * D_FEAT + (size_t)l * 4;
    unsafeAtomicAdd(dr + 0, we * v.x);
    unsafeAtomicAdd(dr + 1, we * v.y);
    unsafeAtomicAdd(dr + 2, we * v.z);
    unsafeAtomicAdd(dr + 3, we * v.w);
}

extern "C" void kernel_launch(void* const* d_in, const int* in_sizes, int n_in,
                              void* d_out, int out_size, void* d_ws, size_t ws_size,
                              hipStream_t stream) {
    const float* x  = (const float*)d_in[0];
    const int*   ei = (const int*)d_in[1];  // [2, E] flat: rows then cols
    const float* ev = (const float*)d_in[2];
    const int* rows = ei;
    const int* cols = ei + N_EDGES;
    float* out = (float*)d_out;

    size_t off = 0;
    auto take = [&](size_t bytes) {
        size_t o = off;
        off = (off + bytes + 15) & ~(size_t)15;
        return o;
    };
    size_t o_ha      = take((size_t)N_NODES * D_FEAT * 2);  // 25.6 MB slice-major A
    size_t o_hb      = take((size_t)N_NODES * D_FEAT * 2);  // 25.6 MB slice-major B
    size_t o_xs      = take((size_t)N_NODES * D_FEAT * 2);  // 25.6 MB xs = 0.1x
    size_t o_rowptr  = take((size_t)(N_NODES + 1) * 4);
    size_t o_cursor  = take((size_t)N_NODES * 4);
    size_t o_partial = take((size_t)SCAN_NBLK * 4);
    size_t o_csr     = take((size_t)N_EDGES * 8);
    size_t need_slice = off;
    size_t need_r3 = need_slice - (size_t)N_NODES * D_FEAT * 2;

    const int edge_blocks_1t = (N_EDGES + 255) / 256;  // 6250

    char* wsb = (char*)d_ws;
    if (ws_size >= need_slice) {
        unsigned* hA      = (unsigned*)(wsb + o_ha);
        unsigned* hB      = (unsigned*)(wsb + o_hb);
        unsigned* xs      = (unsigned*)(wsb + o_xs);
        int*      row_ptr = (int*)(wsb + o_rowptr);
        int*      cursor  = (int*)(wsb + o_cursor);
        int*      partial = (int*)(wsb + o_partial);
        int2*     csr     = (int2*)(wsb + o_csr);

        hipMemsetAsync(cursor, 0, (size_t)N_NODES * 4, stream);
        hist_kernel<<<edge_blocks_1t, 256, 0, stream>>>(rows, cursor);
        scan_partial<<<SCAN_NBLK, 256, 0, stream>>>(cursor, partial);
        scan_top<<<1, 256, 0, stream>>>(partial);
        scan_final<<<SCAN_NBLK, 256, 0, stream>>>(cursor, partial, row_ptr);
        scatter_kernel<<<edge_blocks_1t, 256, 0, stream>>>(rows, cols, ev, cursor, csr);
        prep_x<<<(N_NODES * 64 + 255) / 256, 256, 0, stream>>>((const float2*)x, hA, xs);

        const long long* csr8 = (const long long*)csr;
        for (int k = 0; k < K_STEPS - 1; ++k) {
            const unsigned* src = (k & 1) ? hB : hA;
            unsigned* dst = (k & 1) ? hA : hB;
            slice_spmm<false><<<SLICE_BLOCKS, 256, 0, stream>>>(row_ptr, csr8, xs,
                                                                src, dst, out);
        }
        // k=9: src = hB (k odd), write fp32 node-major to d_out
        slice_spmm<true><<<SLICE_BLOCKS, 256, 0, stream>>>(row_ptr, csr8, xs,
                                                           hB, hA, out);
    } else if (ws_size >= need_r3) {
        // R3 path: node-major bf16 ping-pong (A,B) + CSR
        unsigned* hA      = (unsigned*)(wsb + o_ha);
        unsigned* hB      = (unsigned*)(wsb + o_hb);
        int*      row_ptr = (int*)(wsb + o_rowptr - (size_t)N_NODES * D_FEAT * 2);
        int*      cursor  = (int*)(wsb + o_cursor - (size_t)N_NODES * D_FEAT * 2);
        int*      partial = (int*)(wsb + o_partial - (size_t)N_NODES * D_FEAT * 2);
        int2*     csr     = (int2*)(wsb + o_csr - (size_t)N_NODES * D_FEAT * 2);

        hipMemsetAsync(cursor, 0, (size_t)N_NODES * 4, stream);
        hist_kernel<<<edge_blocks_1t, 256, 0, stream>>>(rows, cursor);
        scan_partial<<<SCAN_NBLK, 256, 0, stream>>>(cursor, partial);
        scan_top<<<1, 256, 0, stream>>>(partial);
        scan_final<<<SCAN_NBLK, 256, 0, stream>>>(cursor, partial, row_ptr);
        scatter_kernel<<<edge_blocks_1t, 256, 0, stream>>>(rows, cols, ev, cursor, csr);

        const int row_blocks = (N_NODES * 64 + 255) / 256;
        const float2* x2 = (const float2*)x;
        row_spmm_t<false, true><<<row_blocks, 256, 0, stream>>>(row_ptr, csr, x2,
                                                                (const void*)x, hA);
        for (int k = 1; k <= 8; ++k) {
            const void* src = (k & 1) ? (void*)hA : (void*)hB;
            void* dst = (k & 1) ? (void*)hB : (void*)hA;
            row_spmm_t<true, true><<<row_blocks, 256, 0, stream>>>(row_ptr, csr, x2, src, dst);
        }
        row_spmm_t<true, false><<<row_blocks, 256, 0, stream>>>(row_ptr, csr, x2,
                                                                (const void*)hA, (void*)out);
    } else {
        float* wsf = (float*)d_ws;
        const int n4 = N_NODES * D_FEAT / 4;
        const int init_blocks = (n4 + 255) / 256;
        const int edge_blocks = (N_EDGES * 32 + 255) / 256;
        for (int k = 0; k < K_STEPS; ++k) {
            const float* src = (k == 0) ? x : ((k & 1) ? wsf : out);
            float* dst = (k & 1) ? out : wsf;
            init_step<<<init_blocks, 256, 0, stream>>>((const float4*)x, (float4*)dst, n4);
            edge_scatter<<<edge_blocks, 256, 0, stream>>>(rows, cols, ev, src, dst);
        }
    }
}